// Round 10
// baseline (128.845 us; speedup 1.0000x reference)
//
#include <hip/hip_runtime.h>

// Bicubic (Catmull-Rom) warped interpolation.
// LDS-tiled, fp32 DUAL-PHASE float2 layout + ds_read2_b64 tap reads.
// img/delta_x/delta_y: [B,C,H,W] fp32; out: fp32 clipped to [0,1]. H=W=1024.
// 64x64 output tile / 256-thread block. 76x81-float patch staged in LDS as
// TWO phase-shifted float2 copies:
//   copy0 pair j = floats (2j, 2j+1); copy1 pair j = (2j+1, 2j+2)
// Any 4-tap row window lx..lx+3 = 2 ADJACENT float2s of copy (lx&1) at pair
// lx>>1 -> one ds_read2_b64 per tap row = 4 LDS instrs/pixel (vs 16 b32),
// same bank traffic, zero conversion VALU (the R7 f16 mistake).
// Delta loads for all 16 row-iterations hoisted into registers (R6 win).
// Out-of-patch taps (|delta| > ~5) take a rare fp32 global fallback.

#define HD 1024
#define WD 1024
#define TILE 64
#define HALO 6
#define SROWS 76    // staged rows (64 + 2*6)
#define NPAIR 40    // valid float2 pairs per row per copy (covers floats 0..80)
#define PSTR2 41    // float2 stride per row
#define COFF2 3116  // copy1 offset in float2 (76*41)

__device__ __forceinline__ float cubic_gather_global(
    const float* __restrict__ p, int x0, int y0,
    float wxm1, float wx0, float wx1, float wx2,
    float wym1, float wy0, float wy1, float wy2)
{
    int cx0 = min(max(x0 - 1, 0), WD - 1);
    int cx1 = min(max(x0,     0), WD - 1);
    int cx2 = min(max(x0 + 1, 0), WD - 1);
    int cx3 = min(max(x0 + 2, 0), WD - 1);
    int cy0 = min(max(y0 - 1, 0), HD - 1);
    int cy1 = min(max(y0,     0), HD - 1);
    int cy2 = min(max(y0 + 1, 0), HD - 1);
    int cy3 = min(max(y0 + 2, 0), HD - 1);
    const float* r0 = p + (size_t)cy0 * WD;
    const float* r1 = p + (size_t)cy1 * WD;
    const float* r2 = p + (size_t)cy2 * WD;
    const float* r3 = p + (size_t)cy3 * WD;
    float s0 = wxm1 * r0[cx0] + wx0 * r0[cx1] + wx1 * r0[cx2] + wx2 * r0[cx3];
    float s1 = wxm1 * r1[cx0] + wx0 * r1[cx1] + wx1 * r1[cx2] + wx2 * r1[cx3];
    float s2 = wxm1 * r2[cx0] + wx0 * r2[cx1] + wx1 * r2[cx2] + wx2 * r2[cx3];
    float s3 = wxm1 * r3[cx0] + wx0 * r3[cx1] + wx1 * r3[cx2] + wx2 * r3[cx3];
    return wym1 * s0 + wy0 * s1 + wy1 * s2 + wy2 * s3;
}

__global__ __launch_bounds__(256) void bicubic_tile_kernel(
    const float* __restrict__ img,
    const float* __restrict__ dxp,
    const float* __restrict__ dyp,
    float* __restrict__ out)
{
    __shared__ float2 sm2[2 * COFF2];   // 49.9 KB

    const int bx = blockIdx.x * TILE;
    const int by = blockIdx.y * TILE;
    const int plane = blockIdx.z;
    const float* __restrict__ p = img + (size_t)plane * (size_t)(HD * WD);

    const int gx0 = bx - HALO;
    const int gy0 = by - HALO;
    const int tid = threadIdx.x;

    // ---- stage 76 rows x (80 floats + 1) as dual-phase float2 copies ----
    if (gx0 >= 0 && gx0 + 80 <= WD - 1) {
        // interior: float4 + 1 scalar load per 4-float quad (20 quads/row)
        for (int s = tid; s < SROWS * 20; s += 256) {
            int r = s / 20;
            int q = s - r * 20;
            int gy = min(max(gy0 + r, 0), HD - 1);
            const float* rowp = p + (size_t)gy * WD + gx0;
            float4 v = *reinterpret_cast<const float4*>(rowp + 4 * q);
            float v4 = rowp[4 * q + 4];
            int b = r * PSTR2 + 2 * q;
            sm2[b]             = make_float2(v.x, v.y);  // copy0: (4q,   4q+1)
            sm2[b + 1]         = make_float2(v.z, v.w);  // copy0: (4q+2, 4q+3)
            sm2[COFF2 + b]     = make_float2(v.y, v.z);  // copy1: (4q+1, 4q+2)
            sm2[COFF2 + b + 1] = make_float2(v.w, v4);   // copy1: (4q+3, 4q+4)
        }
    } else {
        // x-edge tile: per-pair scalar staging with clamp
        for (int s = tid; s < SROWS * NPAIR; s += 256) {
            int r = s / NPAIR;
            int j = s - r * NPAIR;
            int gy = min(max(gy0 + r, 0), HD - 1);
            const float* rowp = p + (size_t)gy * WD;
            int e0 = min(max(gx0 + 2 * j,     0), WD - 1);
            int e1 = min(max(gx0 + 2 * j + 1, 0), WD - 1);
            int e2 = min(max(gx0 + 2 * j + 2, 0), WD - 1);
            float v0 = rowp[e0], v1 = rowp[e1], v2 = rowp[e2];
            int b = r * PSTR2 + j;
            sm2[b]         = make_float2(v0, v1);
            sm2[COFF2 + b] = make_float2(v1, v2);
        }
    }
    __syncthreads();

    // ---- compute: lane = column (64 consecutive cols/wave), 16 rows/thread
    const int col = bx + (tid & 63);
    const int rbase = by + (tid >> 6);
    const int didx0 = (plane << 20) | (rbase << 10) | col;

    // hoisted delta loads (R6 win: HBM latency hides under compute)
    float vdx[16], vdy[16];
    #pragma unroll
    for (int it = 0; it < 16; ++it) {
        vdx[it] = dxp[didx0 + it * 4096];
        vdy[it] = dyp[didx0 + it * 4096];
    }

    // x_map = ((x + dx - 512)/511 + 1)*511.5 == (x-512)*sc + 511.5 + dx*sc
    const float sc = 511.5f / 511.0f;
    const float colA = ((float)col - 512.0f) * sc + 511.5f;
    const float yA0 = ((float)rbase - 512.0f) * sc + 511.5f;
    const float yStep = 4.0f * sc;

    #pragma unroll
    for (int it = 0; it < 16; ++it) {
        const int didx = didx0 + it * 4096;
        const float ddx = vdx[it];
        const float ddy = vdy[it];

        float x_map = fmaf(ddx, sc, colA);
        float y_map = fmaf(ddy, sc, yA0 + (float)it * yStep);

        float x0f = floorf(x_map);
        float y0f = floorf(y_map);
        float tx = x_map - x0f;
        float ty = y_map - y0f;
        int x0 = (int)x0f;
        int y0 = (int)y0f;

        float tx2 = tx * tx, tx3 = tx2 * tx;
        float wxm1 = (-tx3 + 2.0f * tx2 - tx) * 0.5f;
        float wx0  = (3.0f * tx3 - 5.0f * tx2 + 2.0f) * 0.5f;
        float wx1  = (-3.0f * tx3 + 4.0f * tx2 + tx) * 0.5f;
        float wx2  = 1.0f - (wxm1 + wx0 + wx1);

        float ty2 = ty * ty, ty3 = ty2 * ty;
        float wym1 = (-ty3 + 2.0f * ty2 - ty) * 0.5f;
        float wy0  = (3.0f * ty3 - 5.0f * ty2 + 2.0f) * 0.5f;
        float wy1  = (-3.0f * ty3 + 4.0f * ty2 + ty) * 0.5f;
        float wy2  = 1.0f - (wym1 + wy0 + wy1);

        const int lx = x0 - 1 - gx0;
        const int ly = y0 - 1 - gy0;
        const bool inb = (lx >= 0) & (lx <= SROWS - 4) & (ly >= 0) & (ly <= SROWS - 4);

        float acc;
        if (inb) {
            // 4 tap rows x one ds_read2_b64 each (copy selected by lx parity)
            const float2* c = sm2 + ((lx & 1) ? COFF2 : 0) + ly * PSTR2 + (lx >> 1);
            float2 r0a = c[0],         r0b = c[1];
            float2 r1a = c[PSTR2],     r1b = c[PSTR2 + 1];
            float2 r2a = c[2 * PSTR2], r2b = c[2 * PSTR2 + 1];
            float2 r3a = c[3 * PSTR2], r3b = c[3 * PSTR2 + 1];
            float s0 = wxm1 * r0a.x + wx0 * r0a.y + wx1 * r0b.x + wx2 * r0b.y;
            float s1 = wxm1 * r1a.x + wx0 * r1a.y + wx1 * r1b.x + wx2 * r1b.y;
            float s2 = wxm1 * r2a.x + wx0 * r2a.y + wx1 * r2b.x + wx2 * r2b.y;
            float s3 = wxm1 * r3a.x + wx0 * r3a.y + wx1 * r3b.x + wx2 * r3b.y;
            acc = wym1 * s0 + wy0 * s1 + wy1 * s2 + wy2 * s3;
        } else {
            acc = cubic_gather_global(p, x0, y0, wxm1, wx0, wx1, wx2,
                                      wym1, wy0, wy1, wy2);
        }
        out[didx] = fminf(fmaxf(acc, 0.0f), 1.0f);
    }
}

extern "C" void kernel_launch(void* const* d_in, const int* in_sizes, int n_in,
                              void* d_out, int out_size, void* d_ws, size_t ws_size,
                              hipStream_t stream) {
    const float* img = (const float*)d_in[0];
    const float* dxp = (const float*)d_in[1];
    const float* dyp = (const float*)d_in[2];
    float* out = (float*)d_out;

    const int planes = in_sizes[0] / (HD * WD);  // B*C = 24
    dim3 grid(WD / TILE, HD / TILE, planes);
    bicubic_tile_kernel<<<grid, 256, 0, stream>>>(img, dxp, dyp, out);
}

// Round 11
// 92.931 us; speedup vs baseline: 1.3865x; 1.3865x over previous
//
#include <hip/hip_runtime.h>

// Bicubic (Catmull-Rom) warped interpolation, LDS-tiled (R6 structure).
// img/delta_x/delta_y: [B,C,H,W] fp32; out: fp32 clipped to [0,1]. H=W=1024.
// 64x64 output tile / 256-thread block; 80x80 fp32 patch in LDS.
// KEY CHANGE vs R6: LDS row stride 96 (96 mod 32 == 0) so a tap's bank index
// is (lx mod 32) = lane + round(dx) ONLY -- the y-jitter (round(dy) * stride)
// vanishes from the bank calc entirely. Strides 83/84/97 all mixed both
// jitters -> quasi-random banks -> ~4 extra cyc per ds_read (2.3-2.5e7
// conflict cycles). Lane = column; delta loads hoisted (R6 win).
// Out-of-patch taps (|delta| > ~6) take a rare fp32 global fallback.

#define HD 1024
#define WD 1024
#define TILE 64
#define HALO 8
#define SROWS 80   // staged rows & cols of valid data
#define SSTR 96    // LDS row stride in floats; 96 % 32 == 0 -> bank = lx % 32

__device__ __forceinline__ float cubic_gather_global(
    const float* __restrict__ p, int x0, int y0,
    float wxm1, float wx0, float wx1, float wx2,
    float wym1, float wy0, float wy1, float wy2)
{
    int cx0 = min(max(x0 - 1, 0), WD - 1);
    int cx1 = min(max(x0,     0), WD - 1);
    int cx2 = min(max(x0 + 1, 0), WD - 1);
    int cx3 = min(max(x0 + 2, 0), WD - 1);
    int cy0 = min(max(y0 - 1, 0), HD - 1);
    int cy1 = min(max(y0,     0), HD - 1);
    int cy2 = min(max(y0 + 1, 0), HD - 1);
    int cy3 = min(max(y0 + 2, 0), HD - 1);
    const float* r0 = p + (size_t)cy0 * WD;
    const float* r1 = p + (size_t)cy1 * WD;
    const float* r2 = p + (size_t)cy2 * WD;
    const float* r3 = p + (size_t)cy3 * WD;
    float s0 = wxm1 * r0[cx0] + wx0 * r0[cx1] + wx1 * r0[cx2] + wx2 * r0[cx3];
    float s1 = wxm1 * r1[cx0] + wx0 * r1[cx1] + wx1 * r1[cx2] + wx2 * r1[cx3];
    float s2 = wxm1 * r2[cx0] + wx0 * r2[cx1] + wx1 * r2[cx2] + wx2 * r2[cx3];
    float s3 = wxm1 * r3[cx0] + wx0 * r3[cx1] + wx1 * r3[cx2] + wx2 * r3[cx3];
    return wym1 * s0 + wy0 * s1 + wy1 * s2 + wy2 * s3;
}

__global__ __launch_bounds__(256) void bicubic_tile_kernel(
    const float* __restrict__ img,
    const float* __restrict__ dxp,
    const float* __restrict__ dyp,
    float* __restrict__ out)
{
    __shared__ float sm[SROWS * SSTR];   // 30.7 KB -> 5 blocks/CU

    const int bx = blockIdx.x * TILE;
    const int by = blockIdx.y * TILE;
    const int plane = blockIdx.z;
    const float* __restrict__ p = img + (size_t)plane * (size_t)(HD * WD);

    const int gx0 = bx - HALO;
    const int gy0 = by - HALO;
    const int tid = threadIdx.x;

    // ---- stage 80x80 patch at (gy0, gx0) into LDS (edge-clamped) ----
    if (gx0 >= 0 && gx0 + SROWS <= WD) {
        for (int s = tid; s < SROWS * (SROWS / 4); s += 256) {
            int r = s / (SROWS / 4);
            int q = s - r * (SROWS / 4);
            int gy = min(max(gy0 + r, 0), HD - 1);
            float4 v = *reinterpret_cast<const float4*>(p + (size_t)gy * WD + gx0 + 4 * q);
            int b = r * SSTR + 4 * q;
            sm[b + 0] = v.x; sm[b + 1] = v.y; sm[b + 2] = v.z; sm[b + 3] = v.w;
        }
    } else {
        for (int s = tid; s < SROWS * SROWS; s += 256) {
            int r = s / SROWS;
            int c = s - r * SROWS;
            int gy = min(max(gy0 + r, 0), HD - 1);
            int gx = min(max(gx0 + c, 0), WD - 1);
            sm[r * SSTR + c] = p[(size_t)gy * WD + gx];
        }
    }
    __syncthreads();

    // ---- compute: lane = column (64 consecutive cols/wave), 16 rows/thread
    const int col = bx + (tid & 63);
    const int rbase = by + (tid >> 6);
    const int didx0 = (plane << 20) | (rbase << 10) | col;

    // hoisted delta loads (R6 win: HBM latency hides under compute)
    float vdx[16], vdy[16];
    #pragma unroll
    for (int it = 0; it < 16; ++it) {
        vdx[it] = dxp[didx0 + it * 4096];
        vdy[it] = dyp[didx0 + it * 4096];
    }

    // x_map = ((x + dx - 512)/511 + 1)*511.5 == (x-512)*sc + 511.5 + dx*sc
    const float sc = 511.5f / 511.0f;
    const float colA = ((float)col - 512.0f) * sc + 511.5f;
    const float yA0 = ((float)rbase - 512.0f) * sc + 511.5f;
    const float yStep = 4.0f * sc;

    #pragma unroll
    for (int it = 0; it < 16; ++it) {
        const int didx = didx0 + it * 4096;
        const float ddx = vdx[it];
        const float ddy = vdy[it];

        float x_map = fmaf(ddx, sc, colA);
        float y_map = fmaf(ddy, sc, yA0 + (float)it * yStep);

        float x0f = floorf(x_map);
        float y0f = floorf(y_map);
        float tx = x_map - x0f;
        float ty = y_map - y0f;
        int x0 = (int)x0f;
        int y0 = (int)y0f;

        float tx2 = tx * tx, tx3 = tx2 * tx;
        float wxm1 = (-tx3 + 2.0f * tx2 - tx) * 0.5f;
        float wx0  = (3.0f * tx3 - 5.0f * tx2 + 2.0f) * 0.5f;
        float wx1  = (-3.0f * tx3 + 4.0f * tx2 + tx) * 0.5f;
        float wx2  = 1.0f - (wxm1 + wx0 + wx1);

        float ty2 = ty * ty, ty3 = ty2 * ty;
        float wym1 = (-ty3 + 2.0f * ty2 - ty) * 0.5f;
        float wy0  = (3.0f * ty3 - 5.0f * ty2 + 2.0f) * 0.5f;
        float wy1  = (-3.0f * ty3 + 4.0f * ty2 + ty) * 0.5f;
        float wy2  = 1.0f - (wym1 + wy0 + wy1);

        // raw tap window (LDS holds edge-clamped values; no per-tap clamps)
        const int lx = x0 - 1 - gx0;
        const int ly = y0 - 1 - gy0;
        const bool inb = (lx >= 0) & (lx <= SROWS - 4) & (ly >= 0) & (ly <= SROWS - 4);

        float acc;
        if (inb) {
            const float* b = &sm[ly * SSTR + lx];
            float s0 = wxm1 * b[0 * SSTR + 0] + wx0 * b[0 * SSTR + 1] + wx1 * b[0 * SSTR + 2] + wx2 * b[0 * SSTR + 3];
            float s1 = wxm1 * b[1 * SSTR + 0] + wx0 * b[1 * SSTR + 1] + wx1 * b[1 * SSTR + 2] + wx2 * b[1 * SSTR + 3];
            float s2 = wxm1 * b[2 * SSTR + 0] + wx0 * b[2 * SSTR + 1] + wx1 * b[2 * SSTR + 2] + wx2 * b[2 * SSTR + 3];
            float s3 = wxm1 * b[3 * SSTR + 0] + wx0 * b[3 * SSTR + 1] + wx1 * b[3 * SSTR + 2] + wx2 * b[3 * SSTR + 3];
            acc = wym1 * s0 + wy0 * s1 + wy1 * s2 + wy2 * s3;
        } else {
            acc = cubic_gather_global(p, x0, y0, wxm1, wx0, wx1, wx2,
                                      wym1, wy0, wy1, wy2);
        }
        out[didx] = fminf(fmaxf(acc, 0.0f), 1.0f);
    }
}

extern "C" void kernel_launch(void* const* d_in, const int* in_sizes, int n_in,
                              void* d_out, int out_size, void* d_ws, size_t ws_size,
                              hipStream_t stream) {
    const float* img = (const float*)d_in[0];
    const float* dxp = (const float*)d_in[1];
    const float* dyp = (const float*)d_in[2];
    float* out = (float*)d_out;

    const int planes = in_sizes[0] / (HD * WD);  // B*C = 24
    dim3 grid(WD / TILE, HD / TILE, planes);
    bicubic_tile_kernel<<<grid, 256, 0, stream>>>(img, dxp, dyp, out);
}